// Round 3
// baseline (320.705 us; speedup 1.0000x reference)
//
#include <hip/hip_runtime.h>

// phase split: out[p,b,c,i,j] = x[b,c,2i+p/2,2j+p%2]
// x: [B=64, C=3, H=512, W=512] fp32 -> out: [4, B, C, 256, 256] fp32
// Pure permutation; memory-roofline bound (~402 MB traffic -> ~64 us floor @6.3 TB/s).
//
// R1 (unmeasured -- broker timeouts x3, resubmitting unchanged for A/B integrity):
// 4x per-thread unroll (block covers 16 h-rows -> 8 KB contiguous per
// phase plane per block), grid 24576->6144 blocks, non-temporal hints
// (402 MB streaming footprint > 256 MB L3 -> caching is pure pollution).

typedef float f4 __attribute__((ext_vector_type(4)));

__global__ __launch_bounds__(256) void phase_split_kernel(
    const float* __restrict__ x, float* __restrict__ out) {
    constexpr int B = 64, C = 3, H = 512, W = 512;
    constexpr int Hh = H / 2, Wh = W / 2;
    constexpr size_t plane = (size_t)Hh * Wh;              // 65536 floats
    constexpr size_t phase_stride = (size_t)B * C * plane; // floats between phases

    const int lane = threadIdx.x & 63;   // 8-float chunk index within a row
    const int rowi = threadIdx.x >> 6;   // 0..3: row-within-group for this wave
    const int c = blockIdx.y;            // 0..2
    const int b = blockIdx.z;            // 0..63
    const int h0 = (blockIdx.x << 4) + rowi;  // block covers rows [16q, 16q+16)

    const float* xbase = x + (((size_t)b * C + c) * H) * (size_t)W;
    float* obase = out + ((size_t)b * C + c) * plane;

#pragma unroll
    for (int k = 0; k < 4; ++k) {
        const int h = h0 + (k << 2);     // rowi + {0,4,8,12}
        const int dy = h & 1;            // vertical phase
        const int i  = h >> 1;           // output row

        // Coalesced read: lane reads 8 consecutive floats (2 x dwordx4 = 32 B);
        // the wave reads one full 2 KB input row.
        const f4* src = reinterpret_cast<const f4*>(xbase + (size_t)h * W)
                        + (size_t)lane * 2;
        const f4 a0 = __builtin_nontemporal_load(src);
        const f4 a1 = __builtin_nontemporal_load(src + 1);

        // Deinterleave even/odd columns -> two contiguous dwordx4 stores.
        const f4 ev = {a0.x, a0.z, a1.x, a1.z};  // cols 2j   -> phase 2*dy+0
        const f4 od = {a0.y, a0.w, a1.y, a1.w};  // cols 2j+1 -> phase 2*dy+1

        // out index: ((p*B + b)*C + c)*plane + i*Wh + 4*lane
        float* dst = obase + (size_t)(dy << 1) * phase_stride
                           + (size_t)i * Wh + (size_t)lane * 4;
        __builtin_nontemporal_store(ev, reinterpret_cast<f4*>(dst));
        __builtin_nontemporal_store(od, reinterpret_cast<f4*>(dst + phase_stride));
    }
}

extern "C" void kernel_launch(void* const* d_in, const int* in_sizes, int n_in,
                              void* d_out, int out_size, void* d_ws, size_t ws_size,
                              hipStream_t stream) {
    const float* x = (const float*)d_in[0];
    float* out = (float*)d_out;
    dim3 grid(32, 3, 64);   // 16-row groups, C, B
    dim3 block(256);
    phase_split_kernel<<<grid, block, 0, stream>>>(x, out);
}

// Round 4
// 319.483 us; speedup vs baseline: 1.0038x; 1.0038x over previous
//
#include <hip/hip_runtime.h>

// phase split: out[p,b,c,i,j] = x[b,c,2i+p/2,2j+p%2]
// x: [B=64, C=3, H=512, W=512] fp32 -> out: [4, B, C, 256, 256] fp32
// Pure permutation; 402.7 MB traffic -> ~61-64 us mixed-stream floor.
//
// Measured decomposition (R3 rocprof): reported dur_us includes 2x ~123 us
// harness fill dispatches (805 MB @ 6.58 TB/s each); kernel itself ~75 us
// (~82% of achievable). R4: wave owns 8 CONSECUTIVE output rows of one
// dy-parity -> 8 KB sequential write stream per phase plane per wave
// (was 1 KB bursts stride-2 KB), read jumps shrink 8 KB -> 4 KB.

typedef float f4 __attribute__((ext_vector_type(4)));

__global__ __launch_bounds__(256) void phase_split_kernel(
    const float* __restrict__ x, float* __restrict__ out) {
    constexpr int B = 64, C = 3, H = 512, W = 512;
    constexpr int Hh = H / 2, Wh = W / 2;
    constexpr size_t plane = (size_t)Hh * Wh;              // 65536 floats
    constexpr size_t phase_stride = (size_t)B * C * plane; // floats between phases

    const int lane = threadIdx.x & 63;   // 8-float chunk index within a row
    const int w    = threadIdx.x >> 6;   // wave id 0..3
    const int dy   = w & 1;              // vertical phase parity this wave owns
    const int rh   = w >> 1;             // which 8-row half of the block's i-range
    const int c = blockIdx.y;            // 0..2
    const int b = blockIdx.z;            // 0..63

    // Block covers output rows i in [16*bx, 16*bx+16) for BOTH dy parities
    // (input rows h in [32*bx, 32*bx+32)). This wave: 8 consecutive i.
    const int i0 = (blockIdx.x << 4) + (rh << 3);

    const float* xbase = x + (((size_t)b * C + c) * H) * (size_t)W;
    // Base of phase p = 2*dy (even-column phase) for this (b, c).
    float* obase = out + (((size_t)(dy << 1) * B + b) * C + c) * plane;

#pragma unroll
    for (int k = 0; k < 8; ++k) {
        const int i = i0 + k;            // consecutive output rows
        const int h = (i << 1) + dy;     // input row

        // Coalesced read: lane reads 8 consecutive floats (2 x dwordx4 = 32 B);
        // the wave reads one full 2 KB input row.
        const f4* src = reinterpret_cast<const f4*>(xbase + (size_t)h * W)
                        + (size_t)lane * 2;
        const f4 a0 = __builtin_nontemporal_load(src);
        const f4 a1 = __builtin_nontemporal_load(src + 1);

        // Deinterleave even/odd columns -> two contiguous dwordx4 stores.
        const f4 ev = {a0.x, a0.z, a1.x, a1.z};  // cols 2j   -> phase 2*dy+0
        const f4 od = {a0.y, a0.w, a1.y, a1.w};  // cols 2j+1 -> phase 2*dy+1

        // Wave-sequential: row i lands right after row i-1 in both planes.
        float* dst = obase + (size_t)i * Wh + (size_t)lane * 4;
        __builtin_nontemporal_store(ev, reinterpret_cast<f4*>(dst));
        __builtin_nontemporal_store(od, reinterpret_cast<f4*>(dst + phase_stride));
    }
}

extern "C" void kernel_launch(void* const* d_in, const int* in_sizes, int n_in,
                              void* d_out, int out_size, void* d_ws, size_t ws_size,
                              hipStream_t stream) {
    const float* x = (const float*)d_in[0];
    float* out = (float*)d_out;
    dim3 grid(16, 3, 64);   // 16 output-row groups, C, B
    dim3 block(256);
    phase_split_kernel<<<grid, block, 0, stream>>>(x, out);
}